// Round 1
// baseline (1239.789 us; speedup 1.0000x reference)
//
#include <hip/hip_runtime.h>

#define NB 4
#define NH 12
#define SL 2048
#define DK 64
#define SK 104   // LDS row stride (elements): 208 B = 16*13 -> b128-aligned, 2-way-free banks
#define QB 128   // Q rows per workgroup
#define CT 64    // score columns per tile

typedef __attribute__((ext_vector_type(8))) short short8;
typedef __attribute__((ext_vector_type(4))) float floatx4;

__device__ __forceinline__ unsigned short f2bf(float x) {
    union { float f; unsigned int u; } c; c.f = x;
    unsigned int u = c.u;
    u += 0x7fffu + ((u >> 16) & 1u);   // RNE
    return (unsigned short)(u >> 16);
}

__global__ __launch_bounds__(256) void sdpa_fused(
    const float* __restrict__ Qp, const float* __restrict__ Kp,
    const float* __restrict__ Vp, const float* __restrict__ Mp,
    float* __restrict__ ctx_out, float* __restrict__ attn_out)
{
    __shared__ unsigned short Klds[CT * SK];   // K tile  [n][k]  (bf16)
    __shared__ unsigned short Vtlds[DK * SK];  // V tile  [d][c]  (bf16, transposed)
    __shared__ unsigned short Slds[QB * SK];   // S'' tile [row][c] (bf16) — C->A layout bounce

    const int t    = threadIdx.x;
    const int lid  = t & 15;          // lane & 15
    const int quad = (t >> 4) & 3;    // lane >> 4
    const int wv   = t >> 6;          // wave 0..3
    const int qb0  = blockIdx.x * QB;
    const int bh   = blockIdx.y;

    const float* Qb = Qp + (size_t)bh * SL * DK;
    const float* Kb = Kp + (size_t)bh * SL * DK;
    const float* Vb = Vp + (size_t)bh * SL * DK;
    const float* Mb = Mp + (size_t)(bh / NH) * SL * SL;

    // Q fragments (MFMA A operand), kernel-lifetime registers.
    // A layout: m = lane&15, k = kstep*32 + quad*8 + j
    short8 qf[2][2];
    #pragma unroll
    for (int ms = 0; ms < 2; ++ms) {
        #pragma unroll
        for (int ks = 0; ks < 2; ++ks) {
            const float* src = Qb + (size_t)(qb0 + wv*32 + ms*16 + lid) * DK + ks*32 + quad*8;
            short8 q;
            #pragma unroll
            for (int i = 0; i < 8; ++i) q[i] = (short)f2bf(src[i]);
            qf[ms][ks] = q;
        }
    }

    floatx4 ctx[2][4];
    #pragma unroll
    for (int ms = 0; ms < 2; ++ms)
        #pragma unroll
        for (int nd = 0; nd < 4; ++nd)
            ctx[ms][nd] = (floatx4){0.f, 0.f, 0.f, 0.f};

    float rsp[8];
    #pragma unroll
    for (int i = 0; i < 8; ++i) rsp[i] = 0.f;

    // ================= phase 1: row sums + unnormalized context =================
    for (int ct = 0; ct < SL / CT; ++ct) {
        __syncthreads();
        {   // stage K tile -> bf16 LDS, [n][k]
            const int n = t & 63, c0 = (t >> 6) * 16;
            const float* src = Kb + (size_t)(ct * CT + n) * DK + c0;
            float f[16];
            #pragma unroll
            for (int i = 0; i < 16; ++i) f[i] = src[i];
            short8 p0, p1;
            #pragma unroll
            for (int i = 0; i < 8; ++i) { p0[i] = (short)f2bf(f[i]); p1[i] = (short)f2bf(f[8 + i]); }
            *(short8*)&Klds[n * SK + c0]     = p0;
            *(short8*)&Klds[n * SK + c0 + 8] = p1;
        }
        {   // stage V tile transposed -> bf16 LDS, [d][c]
            const int c = t & 63, d0 = (t >> 6) * 16;
            const float* src = Vb + (size_t)(ct * CT + c) * DK + d0;
            float f[16];
            #pragma unroll
            for (int i = 0; i < 16; ++i) f[i] = src[i];
            #pragma unroll
            for (int i = 0; i < 16; ++i) Vtlds[(d0 + i) * SK + c] = f2bf(f[i]);
        }
        __syncthreads();

        // ---- QK^T tile: per wave 32 rows x 64 cols
        floatx4 sc[2][4];
        #pragma unroll
        for (int ms = 0; ms < 2; ++ms)
            #pragma unroll
            for (int ns = 0; ns < 4; ++ns)
                sc[ms][ns] = (floatx4){0.f, 0.f, 0.f, 0.f};

        #pragma unroll
        for (int ns = 0; ns < 4; ++ns) {
            const short8 kb0 = *(const short8*)&Klds[(ns*16 + lid) * SK +  0 + quad*8];
            const short8 kb1 = *(const short8*)&Klds[(ns*16 + lid) * SK + 32 + quad*8];
            #pragma unroll
            for (int ms = 0; ms < 2; ++ms) {
                sc[ms][ns] = __builtin_amdgcn_mfma_f32_16x16x32_bf16(qf[ms][0], kb0, sc[ms][ns], 0, 0, 0);
                sc[ms][ns] = __builtin_amdgcn_mfma_f32_16x16x32_bf16(qf[ms][1], kb1, sc[ms][ns], 0, 0, 0);
            }
        }

        // ---- exp * mask; row-sum partials; park S'' (bf16) in LDS in A-layout source form
        #pragma unroll
        for (int ms = 0; ms < 2; ++ms) {
            #pragma unroll
            for (int r = 0; r < 4; ++r) {
                const int row_l = wv*32 + ms*16 + quad*4 + r;
                const float* mrow = Mb + (size_t)(qb0 + row_l) * SL + ct * CT + lid;
                #pragma unroll
                for (int ns = 0; ns < 4; ++ns) {
                    const float e = __expf(sc[ms][ns][r] * 0.125f) * mrow[ns * 16];
                    rsp[ms*4 + r] += e;
                    Slds[row_l * SK + ns*16 + lid] = f2bf(e);
                }
            }
        }

        // ---- ctx += S'' @ V   (wave-private rows: no barrier needed for Slds)
        #pragma unroll
        for (int ks2 = 0; ks2 < 2; ++ks2) {
            const short8 af0 = *(const short8*)&Slds[(wv*32 +  0 + lid) * SK + ks2*32 + quad*8];
            const short8 af1 = *(const short8*)&Slds[(wv*32 + 16 + lid) * SK + ks2*32 + quad*8];
            #pragma unroll
            for (int nd = 0; nd < 4; ++nd) {
                const short8 vb = *(const short8*)&Vtlds[(nd*16 + lid) * SK + ks2*32 + quad*8];
                ctx[0][nd] = __builtin_amdgcn_mfma_f32_16x16x32_bf16(af0, vb, ctx[0][nd], 0, 0, 0);
                ctx[1][nd] = __builtin_amdgcn_mfma_f32_16x16x32_bf16(af1, vb, ctx[1][nd], 0, 0, 0);
            }
        }
    }

    // ---- reduce row sums across the 16 lanes holding each row's columns
    float inv[8];
    #pragma unroll
    for (int i = 0; i < 8; ++i) {
        float s = rsp[i];
        s += __shfl_xor(s, 1);
        s += __shfl_xor(s, 2);
        s += __shfl_xor(s, 4);
        s += __shfl_xor(s, 8);
        inv[i] = 1.0f / (s + 1e-8f);
    }

    // ---- normalized context store
    #pragma unroll
    for (int ms = 0; ms < 2; ++ms) {
        #pragma unroll
        for (int r = 0; r < 4; ++r) {
            const int row_g = qb0 + wv*32 + ms*16 + quad*4 + r;
            float* crow = ctx_out + ((size_t)bh * SL + row_g) * DK + lid;
            const float iv = inv[ms*4 + r];
            #pragma unroll
            for (int nd = 0; nd < 4; ++nd)
                crow[nd * 16] = ctx[ms][nd][r] * iv;
        }
    }

    // ================= phase 2: recompute scores, write normalized attn =========
    for (int ct = 0; ct < SL / CT; ++ct) {
        __syncthreads();
        {   // restage K tile
            const int n = t & 63, c0 = (t >> 6) * 16;
            const float* src = Kb + (size_t)(ct * CT + n) * DK + c0;
            float f[16];
            #pragma unroll
            for (int i = 0; i < 16; ++i) f[i] = src[i];
            short8 p0, p1;
            #pragma unroll
            for (int i = 0; i < 8; ++i) { p0[i] = (short)f2bf(f[i]); p1[i] = (short)f2bf(f[8 + i]); }
            *(short8*)&Klds[n * SK + c0]     = p0;
            *(short8*)&Klds[n * SK + c0 + 8] = p1;
        }
        __syncthreads();

        floatx4 sc[2][4];
        #pragma unroll
        for (int ms = 0; ms < 2; ++ms)
            #pragma unroll
            for (int ns = 0; ns < 4; ++ns)
                sc[ms][ns] = (floatx4){0.f, 0.f, 0.f, 0.f};

        #pragma unroll
        for (int ns = 0; ns < 4; ++ns) {
            const short8 kb0 = *(const short8*)&Klds[(ns*16 + lid) * SK +  0 + quad*8];
            const short8 kb1 = *(const short8*)&Klds[(ns*16 + lid) * SK + 32 + quad*8];
            #pragma unroll
            for (int ms = 0; ms < 2; ++ms) {
                sc[ms][ns] = __builtin_amdgcn_mfma_f32_16x16x32_bf16(qf[ms][0], kb0, sc[ms][ns], 0, 0, 0);
                sc[ms][ns] = __builtin_amdgcn_mfma_f32_16x16x32_bf16(qf[ms][1], kb1, sc[ms][ns], 0, 0, 0);
            }
        }

        #pragma unroll
        for (int ms = 0; ms < 2; ++ms) {
            #pragma unroll
            for (int r = 0; r < 4; ++r) {
                const int row_l = wv*32 + ms*16 + quad*4 + r;
                const size_t row_g = (size_t)(qb0 + row_l);
                const float* mrow = Mb + row_g * SL + ct * CT + lid;
                float* arow = attn_out + ((size_t)bh * SL + row_g) * SL + ct * CT + lid;
                const float iv = inv[ms*4 + r];
                #pragma unroll
                for (int ns = 0; ns < 4; ++ns) {
                    const float e = __expf(sc[ms][ns][r] * 0.125f) * mrow[ns * 16];
                    arow[ns * 16] = e * iv;
                }
            }
        }
    }
}

extern "C" void kernel_launch(void* const* d_in, const int* in_sizes, int n_in,
                              void* d_out, int out_size, void* d_ws, size_t ws_size,
                              hipStream_t stream) {
    (void)in_sizes; (void)n_in; (void)out_size; (void)d_ws; (void)ws_size;
    const float* Q = (const float*)d_in[0];
    const float* K = (const float*)d_in[1];
    const float* V = (const float*)d_in[2];
    const float* M = (const float*)d_in[3];
    float* ctx  = (float*)d_out;
    float* attn = ctx + (size_t)NB * NH * SL * DK;
    dim3 grid(SL / QB, NB * NH), block(256);
    hipLaunchKernelGGL(sdpa_fused, grid, block, 0, stream, Q, K, V, M, ctx, attn);
}